// Round 1
// baseline (1854.155 us; speedup 1.0000x reference)
//
#include <hip/hip_runtime.h>
#include <hip/hip_bf16.h>
#include <math.h>

#define B1 2048
#define B2 8192
#define NH 12
#define DH 64
#define DMODEL 768

// ---------------------------------------------------------------------------
// GEMM NT: C[M,N] = A[M,K] * B[N,K]^T   (both A and B row-major, K contiguous)
// 128x128 tile, BK=16, 256 threads, 8x8 micro-tile per thread.
// M % 128 == 0, N % 128 == 0, K % 16 == 0 for our shapes (2048/8192, 768, 768).
// ---------------------------------------------------------------------------
#define GBM 128
#define GBN 128
#define GBK 16

__global__ __launch_bounds__(256) void gemm_nt(const float* __restrict__ A,
                                               const float* __restrict__ B,
                                               float* __restrict__ C,
                                               int M, int N, int K) {
  // +4 pad keeps rows 16B-aligned (132*4=528 bytes, 528%16==0) and breaks
  // power-of-2 striding on the staging writes.
  __shared__ float As[GBK][GBM + 4];
  __shared__ float Bs[GBK][GBN + 4];

  const int tid = threadIdx.x;
  const int m0 = blockIdx.y * GBM;
  const int n0 = blockIdx.x * GBN;

  const int tx = tid & 15;   // col group
  const int ty = tid >> 4;   // row group

  const int lrow = tid >> 2;        // 0..63 (two passes -> 128 rows)
  const int lcol = (tid & 3) << 2;  // 0,4,8,12

  float acc[8][8];
#pragma unroll
  for (int i = 0; i < 8; ++i)
#pragma unroll
    for (int j = 0; j < 8; ++j) acc[i][j] = 0.0f;

  for (int k0 = 0; k0 < K; k0 += GBK) {
#pragma unroll
    for (int i = 0; i < 2; ++i) {
      const int row = lrow + i * 64;
      const float4 a4 = *(const float4*)&A[(size_t)(m0 + row) * K + k0 + lcol];
      As[lcol + 0][row] = a4.x;
      As[lcol + 1][row] = a4.y;
      As[lcol + 2][row] = a4.z;
      As[lcol + 3][row] = a4.w;
      const float4 b4 = *(const float4*)&B[(size_t)(n0 + row) * K + k0 + lcol];
      Bs[lcol + 0][row] = b4.x;
      Bs[lcol + 1][row] = b4.y;
      Bs[lcol + 2][row] = b4.z;
      Bs[lcol + 3][row] = b4.w;
    }
    __syncthreads();

#pragma unroll
    for (int kk = 0; kk < GBK; ++kk) {
      float a[8], b[8];
      *(float4*)&a[0] = *(const float4*)&As[kk][ty * 8];
      *(float4*)&a[4] = *(const float4*)&As[kk][ty * 8 + 4];
      *(float4*)&b[0] = *(const float4*)&Bs[kk][tx * 8];
      *(float4*)&b[4] = *(const float4*)&Bs[kk][tx * 8 + 4];
#pragma unroll
      for (int i = 0; i < 8; ++i)
#pragma unroll
        for (int j = 0; j < 8; ++j) acc[i][j] += a[i] * b[j];
    }
    __syncthreads();
  }

#pragma unroll
  for (int i = 0; i < 8; ++i) {
    float4 c0 = {acc[i][0], acc[i][1], acc[i][2], acc[i][3]};
    float4 c1 = {acc[i][4], acc[i][5], acc[i][6], acc[i][7]};
    float* crow = &C[(size_t)(m0 + ty * 8 + i) * N + n0 + tx * 8];
    *(float4*)&crow[0] = c0;
    *(float4*)&crow[4] = c1;
  }
}

// ---------------------------------------------------------------------------
// Per-head L2 norm: rows of 64 contiguous floats. One wave per row.
// ---------------------------------------------------------------------------
__global__ __launch_bounds__(256) void l2norm_rows64(float* __restrict__ x,
                                                     int nrows) {
  const int row = blockIdx.x * 4 + (threadIdx.x >> 6);
  const int lane = threadIdx.x & 63;
  if (row >= nrows) return;
  float v = x[(size_t)row * 64 + lane];
  float ss = v * v;
#pragma unroll
  for (int off = 32; off > 0; off >>= 1) ss += __shfl_xor(ss, off, 64);
  const float sc = 1.0f / fmaxf(sqrtf(ss), 1e-12f);
  x[(size_t)row * 64 + lane] = v * sc;
}

// ---------------------------------------------------------------------------
// Flash-style attention, fp32.
// Block: 256 threads = one head, 32 queries. Streams keys in 64-chunks.
// Thread (qi = tid&31, g = tid>>5): scores keys g*8..g*8+7, owns output dims
// g*8..g*8+7 for query qi. q row kept in registers (16 x float4).
// ---------------------------------------------------------------------------
#define QT 32
#define KC 64

__global__ __launch_bounds__(256) void attn_kernel(
    const float* __restrict__ q,    // [B1, 768] normalized
    const float* __restrict__ k,    // [B2, 768] normalized
    const float* __restrict__ v,    // [B2, 768]
    float* __restrict__ out,        // [B1, 768]
    const int* __restrict__ invt_p) {
  const float scale = (float)invt_p[0];
  const int h = blockIdx.y;
  const int q0 = blockIdx.x * QT;
  const int tid = threadIdx.x;
  const int qi = tid & 31;
  const int g = tid >> 5;

  __shared__ float Kc[KC][DH + 4];   // stride 68 (16B-aligned rows)
  __shared__ float Vc[KC][DH + 4];
  __shared__ float Ps[QT][KC + 1];   // +1: break 32-way bank conflict
  __shared__ float redA[QT][9];      // chunk max
  __shared__ float redB[QT][9];      // chunk sum

  // q row into registers (duplicated across the 8 g-threads of a query)
  float4 qreg[16];
  const float* qrow = q + (size_t)(q0 + qi) * DMODEL + h * DH;
#pragma unroll
  for (int i = 0; i < 16; ++i) qreg[i] = ((const float4*)qrow)[i];

  float m = -1e30f, l = 0.0f;
  float acc[8] = {0, 0, 0, 0, 0, 0, 0, 0};

  for (int n0 = 0; n0 < B2; n0 += KC) {
    // cooperative K/V chunk load: 64 keys x 64 dims, float4 per thread x4
#pragma unroll
    for (int i = 0; i < 4; ++i) {
      const int flat = tid + i * 256;      // 0..1023 float4 slots
      const int key = flat >> 4;
      const int d4 = (flat & 15) << 2;
      const size_t gaddr = (size_t)(n0 + key) * DMODEL + h * DH + d4;
      *(float4*)&Kc[key][d4] = *(const float4*)&k[gaddr];
      *(float4*)&Vc[key][d4] = *(const float4*)&v[gaddr];
    }
    __syncthreads();

    // scores for my 8 keys
    float s[8];
    float mloc = -1e30f;
#pragma unroll
    for (int kk = 0; kk < 8; ++kk) {
      const int key = g * 8 + kk;
      float d0 = 0.0f;
#pragma unroll
      for (int d4 = 0; d4 < 16; ++d4) {
        const float4 kf = *(const float4*)&Kc[key][d4 << 2];
        const float4 qf = qreg[d4];
        d0 += qf.x * kf.x + qf.y * kf.y + qf.z * kf.z + qf.w * kf.w;
      }
      s[kk] = d0 * scale;
      mloc = fmaxf(mloc, s[kk]);
    }
    redA[qi][g] = mloc;
    __syncthreads();

    float mc = redA[qi][0];
#pragma unroll
    for (int j = 1; j < 8; ++j) mc = fmaxf(mc, redA[qi][j]);
    const float mnew = fmaxf(m, mc);

    float lloc = 0.0f;
#pragma unroll
    for (int kk = 0; kk < 8; ++kk) {
      const float p = __expf(s[kk] - mnew);
      Ps[qi][g * 8 + kk] = p;
      lloc += p;
    }
    redB[qi][g] = lloc;
    __syncthreads();

    float lc = redB[qi][0];
#pragma unroll
    for (int j = 1; j < 8; ++j) lc += redB[qi][j];

    const float alpha = __expf(m - mnew);
    m = mnew;
    l = l * alpha + lc;
#pragma unroll
    for (int j = 0; j < 8; ++j) acc[j] *= alpha;

    // PV: O[qi][g*8..+7] += sum_key Ps[qi][key] * V[key][g*8..+7]
#pragma unroll 8
    for (int key = 0; key < KC; ++key) {
      const float p = Ps[qi][key];
      const float4 v0 = *(const float4*)&Vc[key][g * 8];
      const float4 v1 = *(const float4*)&Vc[key][g * 8 + 4];
      acc[0] += p * v0.x;
      acc[1] += p * v0.y;
      acc[2] += p * v0.z;
      acc[3] += p * v0.w;
      acc[4] += p * v1.x;
      acc[5] += p * v1.y;
      acc[6] += p * v1.z;
      acc[7] += p * v1.w;
    }
    __syncthreads();
  }

  const float inv_l = 1.0f / l;
  float* orow = &out[(size_t)(q0 + qi) * DMODEL + h * DH + g * 8];
  float4 o0 = {acc[0] * inv_l, acc[1] * inv_l, acc[2] * inv_l, acc[3] * inv_l};
  float4 o1 = {acc[4] * inv_l, acc[5] * inv_l, acc[6] * inv_l, acc[7] * inv_l};
  *(float4*)&orow[0] = o0;
  *(float4*)&orow[4] = o1;
}

// ---------------------------------------------------------------------------
// Final row L2 norm over 768 and write to output.
// ---------------------------------------------------------------------------
__global__ __launch_bounds__(256) void l2norm_rows768_out(
    const float* __restrict__ x, float* __restrict__ out) {
  const int row = blockIdx.x;
  const float* xr = &x[(size_t)row * DMODEL];
  float ss = 0.0f;
  float vals[3];
#pragma unroll
  for (int i = 0; i < 3; ++i) {
    vals[i] = xr[threadIdx.x + i * 256];
    ss += vals[i] * vals[i];
  }
#pragma unroll
  for (int off = 32; off > 0; off >>= 1) ss += __shfl_xor(ss, off, 64);
  __shared__ float ws[4];
  if ((threadIdx.x & 63) == 0) ws[threadIdx.x >> 6] = ss;
  __syncthreads();
  const float tot = ws[0] + ws[1] + ws[2] + ws[3];
  const float sc = 1.0f / fmaxf(sqrtf(tot), 1e-12f);
  float* orow = &out[(size_t)row * DMODEL];
#pragma unroll
  for (int i = 0; i < 3; ++i) orow[threadIdx.x + i * 256] = vals[i] * sc;
}

// ---------------------------------------------------------------------------
extern "C" void kernel_launch(void* const* d_in, const int* in_sizes, int n_in,
                              void* d_out, int out_size, void* d_ws,
                              size_t ws_size, hipStream_t stream) {
  const float* x1 = (const float*)d_in[0];
  const float* x2 = (const float*)d_in[1];
  const float* Wq = (const float*)d_in[2];
  const float* Wk = (const float*)d_in[3];
  const float* Wv = (const float*)d_in[4];
  const float* Wo = (const float*)d_in[5];
  const int* invt = (const int*)d_in[6];
  float* outp = (float*)d_out;

  float* q_ws = (float*)d_ws;                          // [2048*768]
  float* k_ws = q_ws + (size_t)B1 * DMODEL;            // [8192*768]
  float* v_ws = k_ws + (size_t)B2 * DMODEL;            // [8192*768]
  float* ao_ws = v_ws + (size_t)B2 * DMODEL;           // [2048*768]
  float* tmp_ws = k_ws;  // k no longer needed after attention

  // projections
  gemm_nt<<<dim3(DMODEL / GBN, B1 / GBM), 256, 0, stream>>>(x1, Wq, q_ws, B1,
                                                            DMODEL, DMODEL);
  gemm_nt<<<dim3(DMODEL / GBN, B2 / GBM), 256, 0, stream>>>(x2, Wk, k_ws, B2,
                                                            DMODEL, DMODEL);
  gemm_nt<<<dim3(DMODEL / GBN, B2 / GBM), 256, 0, stream>>>(x2, Wv, v_ws, B2,
                                                            DMODEL, DMODEL);
  // cosine normalization
  l2norm_rows64<<<(B1 * NH) / 4, 256, 0, stream>>>(q_ws, B1 * NH);
  l2norm_rows64<<<(B2 * NH) / 4, 256, 0, stream>>>(k_ws, B2 * NH);
  // attention
  attn_kernel<<<dim3(B1 / QT, NH), 256, 0, stream>>>(q_ws, k_ws, v_ws, ao_ws,
                                                     invt);
  // output projection + final norm
  gemm_nt<<<dim3(DMODEL / GBN, B1 / GBM), 256, 0, stream>>>(ao_ws, Wo, tmp_ws,
                                                            B1, DMODEL, DMODEL);
  l2norm_rows768_out<<<B1, 256, 0, stream>>>(tmp_ws, outp);
}

// Round 2
// 703.760 us; speedup vs baseline: 2.6346x; 2.6346x over previous
//
#include <hip/hip_runtime.h>
#include <hip/hip_bf16.h>
#include <math.h>

#define B1 2048
#define B2 8192
#define NH 12
#define DH 64
#define DMODEL 768

typedef __attribute__((ext_vector_type(8))) short short8;
typedef __attribute__((ext_vector_type(4))) float floatx4;
typedef __attribute__((ext_vector_type(8))) unsigned short ushort8;

static __device__ __forceinline__ unsigned short f2bf(float f) {
  __bf16 b = (__bf16)f;
  return __builtin_bit_cast(unsigned short, b);
}
static __device__ __forceinline__ float bf2f(unsigned short u) {
  return __builtin_bit_cast(float, ((unsigned)u) << 16);
}

// ---------------------------------------------------------------------------
// GEMM NT: C[M,N] = A[M,K] * B[N,K]^T, fp32 math, fp32 or bf16 store.
// 128x128 tile, BK=16, 256 threads, 8x8 micro-tile.
// ---------------------------------------------------------------------------
#define GBM 128
#define GBN 128
#define GBK 16

template <bool BF16OUT>
__global__ __launch_bounds__(256) void gemm_nt_t(const float* __restrict__ A,
                                                 const float* __restrict__ B,
                                                 void* __restrict__ Cv,
                                                 int M, int N, int K) {
  __shared__ float As[GBK][GBM + 4];
  __shared__ float Bs[GBK][GBN + 4];

  const int tid = threadIdx.x;
  const int m0 = blockIdx.y * GBM;
  const int n0 = blockIdx.x * GBN;
  const int tx = tid & 15;
  const int ty = tid >> 4;
  const int lrow = tid >> 2;
  const int lcol = (tid & 3) << 2;

  float acc[8][8];
#pragma unroll
  for (int i = 0; i < 8; ++i)
#pragma unroll
    for (int j = 0; j < 8; ++j) acc[i][j] = 0.0f;

  for (int k0 = 0; k0 < K; k0 += GBK) {
#pragma unroll
    for (int i = 0; i < 2; ++i) {
      const int row = lrow + i * 64;
      const float4 a4 = *(const float4*)&A[(size_t)(m0 + row) * K + k0 + lcol];
      As[lcol + 0][row] = a4.x;
      As[lcol + 1][row] = a4.y;
      As[lcol + 2][row] = a4.z;
      As[lcol + 3][row] = a4.w;
      const float4 b4 = *(const float4*)&B[(size_t)(n0 + row) * K + k0 + lcol];
      Bs[lcol + 0][row] = b4.x;
      Bs[lcol + 1][row] = b4.y;
      Bs[lcol + 2][row] = b4.z;
      Bs[lcol + 3][row] = b4.w;
    }
    __syncthreads();

#pragma unroll
    for (int kk = 0; kk < GBK; ++kk) {
      float a[8], b[8];
      *(float4*)&a[0] = *(const float4*)&As[kk][ty * 8];
      *(float4*)&a[4] = *(const float4*)&As[kk][ty * 8 + 4];
      *(float4*)&b[0] = *(const float4*)&Bs[kk][tx * 8];
      *(float4*)&b[4] = *(const float4*)&Bs[kk][tx * 8 + 4];
#pragma unroll
      for (int i = 0; i < 8; ++i)
#pragma unroll
        for (int j = 0; j < 8; ++j) acc[i][j] += a[i] * b[j];
    }
    __syncthreads();
  }

#pragma unroll
  for (int i = 0; i < 8; ++i) {
    const size_t crow = (size_t)(m0 + ty * 8 + i) * N + n0 + tx * 8;
    if constexpr (BF16OUT) {
      ushort8 h;
#pragma unroll
      for (int j = 0; j < 8; ++j) h[j] = f2bf(acc[i][j]);
      *(ushort8*)&((unsigned short*)Cv)[crow] = h;
    } else {
      float4 c0 = {acc[i][0], acc[i][1], acc[i][2], acc[i][3]};
      float4 c1 = {acc[i][4], acc[i][5], acc[i][6], acc[i][7]};
      float* cp = &((float*)Cv)[crow];
      *(float4*)&cp[0] = c0;
      *(float4*)&cp[4] = c1;
    }
  }
}

// ---------------------------------------------------------------------------
// In-place per-head L2 norm on bf16 rows of 64. One wave per row.
// ---------------------------------------------------------------------------
__global__ __launch_bounds__(256) void l2norm64_bf(unsigned short* __restrict__ x,
                                                   int nrows) {
  const int row = blockIdx.x * 4 + (threadIdx.x >> 6);
  const int lane = threadIdx.x & 63;
  if (row >= nrows) return;
  const float v = bf2f(x[(size_t)row * 64 + lane]);
  float ss = v * v;
#pragma unroll
  for (int off = 32; off > 0; off >>= 1) ss += __shfl_xor(ss, off, 64);
  const float sc = 1.0f / fmaxf(sqrtf(ss), 1e-12f);
  x[(size_t)row * 64 + lane] = f2bf(v * sc);
}

// ---------------------------------------------------------------------------
// MFMA bf16 attention. Fixed softmax max = invt (cos <= 1): no rescaling,
// partials additive. Block: 1 head, 64 queries, 4 waves (2 qsub x 2 ksub),
// wave = 32q x 64k per chunk. KC=128 keys/chunk. KSPLIT blocks split the
// 8192 keys; combine via f32 atomicAdd into aoacc/lacc (pre-zeroed).
// ---------------------------------------------------------------------------
#define KC 128
#define KSPLIT 2
#define KSTR 72    // K LDS row stride (halves): 144B, 16B-aligned
#define VSTR 136   // Vt LDS row stride (halves): 272B
#define PSTR 72    // P LDS row stride (halves)

__global__ __launch_bounds__(256, 3) void attn_mfma(
    const unsigned short* __restrict__ qb,   // [B1][768] bf16, normalized
    const unsigned short* __restrict__ kb,   // [B2][768] bf16, normalized
    const unsigned short* __restrict__ vt,   // [768][B2] bf16 (v transposed)
    float* __restrict__ aoacc,               // [B1][768] f32, zeroed
    float* __restrict__ lacc,                // [B1][NH] f32, zeroed
    const int* __restrict__ invt_p) {
  __shared__ unsigned short Kl[KC * KSTR];        // 18432 B
  __shared__ unsigned short Vl[DH * VSTR];        // 17408 B
  __shared__ unsigned short Psl[4 * 32 * PSTR];   // 18432 B

  const float scale = (float)invt_p[0];
  const int h = blockIdx.y;
  const int q0 = blockIdx.x * 64;
  const int tid = threadIdx.x;
  const int wave = tid >> 6;
  const int lane = tid & 63;
  const int qsub = wave >> 1;   // 0..1 : which 32 queries
  const int ksub = wave & 1;    // 0..1 : which 64 keys of the chunk
  const int n15 = lane & 15;
  const int quad = lane >> 4;
  const int kz0 = blockIdx.z * (B2 / KSPLIT);

  unsigned short* Ps = &Psl[wave * 32 * PSTR];

  // Q A-fragments: [qtile][kstep], reused over all chunks.
  short8 qf[2][2];
#pragma unroll
  for (int qt = 0; qt < 2; ++qt)
#pragma unroll
    for (int s = 0; s < 2; ++s) {
      const int qrow = q0 + qsub * 32 + qt * 16 + n15;
      qf[qt][s] = *(const short8*)&qb[(size_t)qrow * DMODEL + h * DH + s * 32 + quad * 8];
    }

  floatx4 oacc[2][4];   // [qtile][dtile]
#pragma unroll
  for (int qt = 0; qt < 2; ++qt)
#pragma unroll
    for (int nt = 0; nt < 4; ++nt) oacc[qt][nt] = (floatx4){0.f, 0.f, 0.f, 0.f};
  float lsum[2][4];     // [qtile][reg]
#pragma unroll
  for (int qt = 0; qt < 2; ++qt)
#pragma unroll
    for (int r = 0; r < 4; ++r) lsum[qt][r] = 0.0f;

  for (int c = 0; c < B2 / KSPLIT; c += KC) {
    const int kc0 = kz0 + c;
    __syncthreads();  // previous chunk's LDS reads complete
    // stage K chunk: [128 keys][64 dims] bf16
#pragma unroll
    for (int i = 0; i < 4; ++i) {
      const int slot = i * 256 + tid;
      const int key = slot >> 3, g = slot & 7;
      *(short8*)&Kl[key * KSTR + g * 8] =
          *(const short8*)&kb[(size_t)(kc0 + key) * DMODEL + h * DH + g * 8];
    }
    // stage Vt chunk: [64 dims][128 keys] bf16 (already transposed in global)
#pragma unroll
    for (int i = 0; i < 4; ++i) {
      const int slot = i * 256 + tid;
      const int d = slot >> 4, g = slot & 15;
      *(short8*)&Vl[d * VSTR + g * 8] =
          *(const short8*)&vt[(size_t)(h * DH + d) * B2 + kc0 + g * 8];
    }
    __syncthreads();

    // QK^T -> exp -> P (bf16, per-wave LDS)
#pragma unroll
    for (int nt = 0; nt < 4; ++nt) {
      floatx4 s0 = {0.f, 0.f, 0.f, 0.f}, s1 = {0.f, 0.f, 0.f, 0.f};
#pragma unroll
      for (int ks = 0; ks < 2; ++ks) {
        const short8 bfr = *(const short8*)&Kl[(ksub * 64 + nt * 16 + n15) * KSTR +
                                               ks * 32 + quad * 8];
        s0 = __builtin_amdgcn_mfma_f32_16x16x32_bf16(qf[0][ks], bfr, s0, 0, 0, 0);
        s1 = __builtin_amdgcn_mfma_f32_16x16x32_bf16(qf[1][ks], bfr, s1, 0, 0, 0);
      }
#pragma unroll
      for (int r = 0; r < 4; ++r) {
        const float p0 = __expf(scale * (s0[r] - 1.0f));
        const float p1 = __expf(scale * (s1[r] - 1.0f));
        lsum[0][r] += p0;
        lsum[1][r] += p1;
        Ps[(0 * 16 + quad * 4 + r) * PSTR + nt * 16 + n15] = f2bf(p0);
        Ps[(1 * 16 + quad * 4 + r) * PSTR + nt * 16 + n15] = f2bf(p1);
      }
    }
    // (no barrier: Ps is wave-private)

    // P @ V
#pragma unroll
    for (int ks = 0; ks < 2; ++ks) {
      short8 af[2];
#pragma unroll
      for (int qt = 0; qt < 2; ++qt)
        af[qt] = *(const short8*)&Ps[(qt * 16 + n15) * PSTR + ks * 32 + quad * 8];
#pragma unroll
      for (int nt = 0; nt < 4; ++nt) {
        const short8 bfr = *(const short8*)&Vl[(nt * 16 + n15) * VSTR + ksub * 64 +
                                               ks * 32 + quad * 8];
        oacc[0][nt] = __builtin_amdgcn_mfma_f32_16x16x32_bf16(af[0], bfr, oacc[0][nt], 0, 0, 0);
        oacc[1][nt] = __builtin_amdgcn_mfma_f32_16x16x32_bf16(af[1], bfr, oacc[1][nt], 0, 0, 0);
      }
    }
  }

  // l: reduce over the 16 lanes of each row-group (cols)
#pragma unroll
  for (int qt = 0; qt < 2; ++qt)
#pragma unroll
    for (int r = 0; r < 4; ++r) {
      float v = lsum[qt][r];
      v += __shfl_xor(v, 1, 64);
      v += __shfl_xor(v, 2, 64);
      v += __shfl_xor(v, 4, 64);
      v += __shfl_xor(v, 8, 64);
      lsum[qt][r] = v;
    }

  __syncthreads();  // all LDS reads done; reuse Kl/Vl as scratch
  float* Osc = (float*)Kl;   // [64][65] f32 = 16640 B <= 18432
  float* Lsc = (float*)Vl;   // [64] f32
  if (ksub == 1) {
#pragma unroll
    for (int qt = 0; qt < 2; ++qt) {
#pragma unroll
      for (int nt = 0; nt < 4; ++nt)
#pragma unroll
        for (int r = 0; r < 4; ++r) {
          const int row = qsub * 32 + qt * 16 + quad * 4 + r;
          Osc[row * 65 + nt * 16 + n15] = oacc[qt][nt][r];
        }
      if (n15 == 0)
#pragma unroll
        for (int r = 0; r < 4; ++r)
          Lsc[qsub * 32 + qt * 16 + quad * 4 + r] = lsum[qt][r];
    }
  }
  __syncthreads();
  if (ksub == 0) {
#pragma unroll
    for (int qt = 0; qt < 2; ++qt) {
#pragma unroll
      for (int nt = 0; nt < 4; ++nt)
#pragma unroll
        for (int r = 0; r < 4; ++r) {
          const int row = qsub * 32 + qt * 16 + quad * 4 + r;
          const float v = oacc[qt][nt][r] + Osc[row * 65 + nt * 16 + n15];
          atomicAdd(&aoacc[(size_t)(q0 + row) * DMODEL + h * DH + nt * 16 + n15], v);
        }
      if (n15 == 0)
#pragma unroll
        for (int r = 0; r < 4; ++r) {
          const int row = qsub * 32 + qt * 16 + quad * 4 + r;
          atomicAdd(&lacc[(q0 + row) * NH + h], lsum[qt][r] + Lsc[row]);
        }
    }
  }
}

// ---------------------------------------------------------------------------
// out[q][h*64+d] = aoacc[q][h*64+d] / lacc[q][h]
// ---------------------------------------------------------------------------
__global__ __launch_bounds__(256) void ao_normalize(const float* __restrict__ ao,
                                                    const float* __restrict__ l,
                                                    float* __restrict__ out) {
  const int row = blockIdx.x;
  const int t = threadIdx.x;
#pragma unroll
  for (int i = 0; i < 3; ++i) {
    const int d = t + i * 256;
    out[(size_t)row * DMODEL + d] =
        ao[(size_t)row * DMODEL + d] / l[row * NH + (d >> 6)];
  }
}

// ---------------------------------------------------------------------------
// Final row L2 norm over 768 -> output.
// ---------------------------------------------------------------------------
__global__ __launch_bounds__(256) void l2norm_rows768_out(
    const float* __restrict__ x, float* __restrict__ out) {
  const int row = blockIdx.x;
  const float* xr = &x[(size_t)row * DMODEL];
  float ss = 0.0f;
  float vals[3];
#pragma unroll
  for (int i = 0; i < 3; ++i) {
    vals[i] = xr[threadIdx.x + i * 256];
    ss += vals[i] * vals[i];
  }
#pragma unroll
  for (int off = 32; off > 0; off >>= 1) ss += __shfl_xor(ss, off, 64);
  __shared__ float ws[4];
  if ((threadIdx.x & 63) == 0) ws[threadIdx.x >> 6] = ss;
  __syncthreads();
  const float tot = ws[0] + ws[1] + ws[2] + ws[3];
  const float sc = 1.0f / fmaxf(sqrtf(tot), 1e-12f);
  float* orow = &out[(size_t)row * DMODEL];
#pragma unroll
  for (int i = 0; i < 3; ++i) orow[threadIdx.x + i * 256] = vals[i] * sc;
}

// ---------------------------------------------------------------------------
extern "C" void kernel_launch(void* const* d_in, const int* in_sizes, int n_in,
                              void* d_out, int out_size, void* d_ws,
                              size_t ws_size, hipStream_t stream) {
  const float* x1 = (const float*)d_in[0];
  const float* x2 = (const float*)d_in[1];
  const float* Wq = (const float*)d_in[2];
  const float* Wk = (const float*)d_in[3];
  const float* Wv = (const float*)d_in[4];
  const float* Wo = (const float*)d_in[5];
  const int* invt = (const int*)d_in[6];
  float* outp = (float*)d_out;

  char* ws = (char*)d_ws;
  unsigned short* q_bf = (unsigned short*)(ws);                      // 3145728 B
  unsigned short* k_bf = (unsigned short*)(ws + 3145728);            // 12582912 B
  unsigned short* vt_bf = (unsigned short*)(ws + 15728640);          // 12582912 B
  float* aoacc = (float*)(ws + 28311552);                            // 6291456 B
  float* lacc = (float*)(ws + 34603008);                             // 98304 B
  float* aonorm = (float*)(ws + 34701312);                           // 6291456 B
  float* woout = (float*)(ws + 40992768);                            // 6291456 B

  // projections (fp32 math, bf16 store). v is produced transposed: Wv @ x2^T.
  gemm_nt_t<true><<<dim3(DMODEL / GBN, B1 / GBM), 256, 0, stream>>>(
      x1, Wq, q_bf, B1, DMODEL, DMODEL);
  gemm_nt_t<true><<<dim3(DMODEL / GBN, B2 / GBM), 256, 0, stream>>>(
      x2, Wk, k_bf, B2, DMODEL, DMODEL);
  gemm_nt_t<true><<<dim3(B2 / GBN, DMODEL / GBM), 256, 0, stream>>>(
      Wv, x2, vt_bf, DMODEL, B2, DMODEL);
  // cosine normalization (in-place bf16)
  l2norm64_bf<<<(B1 * NH) / 4, 256, 0, stream>>>(q_bf, B1 * NH);
  l2norm64_bf<<<(B2 * NH) / 4, 256, 0, stream>>>(k_bf, B2 * NH);
  // zero accumulators (ws is poisoned each call)
  hipMemsetAsync(aoacc, 0, (size_t)B1 * DMODEL * sizeof(float), stream);
  hipMemsetAsync(lacc, 0, (size_t)B1 * NH * sizeof(float), stream);
  // attention (MFMA bf16)
  attn_mfma<<<dim3(B1 / 64, NH, KSPLIT), 256, 0, stream>>>(q_bf, k_bf, vt_bf,
                                                           aoacc, lacc, invt);
  ao_normalize<<<B1, 256, 0, stream>>>(aoacc, lacc, aonorm);
  // output projection (fp32) + final norm
  gemm_nt_t<false><<<dim3(DMODEL / GBN, B1 / GBM), 256, 0, stream>>>(
      aonorm, Wo, woout, B1, DMODEL, DMODEL);
  l2norm_rows768_out<<<B1, 256, 0, stream>>>(woout, outp);
}

// Round 3
// 369.693 us; speedup vs baseline: 5.0154x; 1.9036x over previous
//
#include <hip/hip_runtime.h>
#include <hip/hip_bf16.h>
#include <math.h>

#define B1 2048
#define B2 8192
#define NH 12
#define DH 64
#define DMODEL 768

typedef __attribute__((ext_vector_type(8))) short short8;
typedef __attribute__((ext_vector_type(4))) float floatx4;
typedef __attribute__((ext_vector_type(8))) unsigned short ushort8;
typedef __attribute__((ext_vector_type(4))) unsigned short ushort4v;

static __device__ __forceinline__ unsigned short f2bf(float f) {
  __bf16 b = (__bf16)f;
  return __builtin_bit_cast(unsigned short, b);
}
static __device__ __forceinline__ float bf2f(unsigned short u) {
  return __builtin_bit_cast(float, ((unsigned)u) << 16);
}

// ---------------------------------------------------------------------------
// MFMA GEMM NT: C[M,N] = A[M,K]*B[N,K]^T, fp32 inputs converted to bf16.
// 128x128 tile, BK=32, 256 threads = 4 waves (2x2), 64x64 per wave.
// SPLIT: two-sided bf16 hi/lo split (3 MFMAs/k-step) => ~fp32 precision.
// L2N:   per-64-column L2 normalization epilogue (per-head cosine norm).
// F32OUT: store fp32 instead of bf16.
// M,N % 128 == 0; K % 32 == 0.
// ---------------------------------------------------------------------------
#define TSTR 40  // LDS row stride in halves (80B, 16B-aligned, conflict-benign)

template <bool SPLIT, bool L2N, bool F32OUT>
__global__ __launch_bounds__(256) void gemm_mfma(const float* __restrict__ A,
                                                 const float* __restrict__ B,
                                                 void* __restrict__ Cv,
                                                 int M, int N, int K) {
  __shared__ unsigned short Ah[128 * TSTR];
  __shared__ unsigned short Bh[128 * TSTR];
  __shared__ unsigned short Al[SPLIT ? 128 * TSTR : 8];
  __shared__ unsigned short Bl[SPLIT ? 128 * TSTR : 8];

  const int tid = threadIdx.x;
  const int m0 = blockIdx.y * 128;
  const int n0 = blockIdx.x * 128;
  const int wave = tid >> 6;
  const int lane = tid & 63;
  const int wm = wave >> 1;
  const int wn = wave & 1;
  const int n15 = lane & 15;
  const int quad = lane >> 4;

  floatx4 acc[4][4];
#pragma unroll
  for (int i = 0; i < 4; ++i)
#pragma unroll
    for (int j = 0; j < 4; ++j) acc[i][j] = (floatx4){0.f, 0.f, 0.f, 0.f};

  const int r = tid >> 1;          // staging row 0..127
  const int c = (tid & 1) << 2;    // staging col group {0,4}
  // each thread stages 4 float4 per matrix: rows r, cols c + {0,8,16,24}? no:
  // slot layout: 128 rows x 8 float4-cols; thread covers (r, c) for 4 i-steps
  // via slot = i*256 + tid -> r = slot>>3, c4 = slot&7.

  for (int k0 = 0; k0 < K; k0 += 32) {
    __syncthreads();
#pragma unroll
    for (int i = 0; i < 4; ++i) {
      const int slot = i * 256 + tid;
      const int rr = slot >> 3;
      const int cc = (slot & 7) << 2;
      const float4 a4 = *(const float4*)&A[(size_t)(m0 + rr) * K + k0 + cc];
      const float4 b4 = *(const float4*)&B[(size_t)(n0 + rr) * K + k0 + cc];
      ushort4v ah = {f2bf(a4.x), f2bf(a4.y), f2bf(a4.z), f2bf(a4.w)};
      ushort4v bh = {f2bf(b4.x), f2bf(b4.y), f2bf(b4.z), f2bf(b4.w)};
      *(ushort4v*)&Ah[rr * TSTR + cc] = ah;
      *(ushort4v*)&Bh[rr * TSTR + cc] = bh;
      if constexpr (SPLIT) {
        ushort4v al = {f2bf(a4.x - bf2f(ah[0])), f2bf(a4.y - bf2f(ah[1])),
                       f2bf(a4.z - bf2f(ah[2])), f2bf(a4.w - bf2f(ah[3]))};
        ushort4v bl = {f2bf(b4.x - bf2f(bh[0])), f2bf(b4.y - bf2f(bh[1])),
                       f2bf(b4.z - bf2f(bh[2])), f2bf(b4.w - bf2f(bh[3]))};
        *(ushort4v*)&Al[rr * TSTR + cc] = al;
        *(ushort4v*)&Bl[rr * TSTR + cc] = bl;
      }
    }
    __syncthreads();

    short8 afh[4], afl[4];
#pragma unroll
    for (int mt = 0; mt < 4; ++mt) {
      const int arow = wm * 64 + mt * 16 + n15;
      afh[mt] = *(const short8*)&Ah[arow * TSTR + quad * 8];
      if constexpr (SPLIT) afl[mt] = *(const short8*)&Al[arow * TSTR + quad * 8];
    }
#pragma unroll
    for (int nt = 0; nt < 4; ++nt) {
      const int brow = wn * 64 + nt * 16 + n15;
      const short8 bfh = *(const short8*)&Bh[brow * TSTR + quad * 8];
      if constexpr (SPLIT) {
        const short8 bfl = *(const short8*)&Bl[brow * TSTR + quad * 8];
#pragma unroll
        for (int mt = 0; mt < 4; ++mt) {
          acc[mt][nt] = __builtin_amdgcn_mfma_f32_16x16x32_bf16(afh[mt], bfh, acc[mt][nt], 0, 0, 0);
          acc[mt][nt] = __builtin_amdgcn_mfma_f32_16x16x32_bf16(afh[mt], bfl, acc[mt][nt], 0, 0, 0);
          acc[mt][nt] = __builtin_amdgcn_mfma_f32_16x16x32_bf16(afl[mt], bfh, acc[mt][nt], 0, 0, 0);
        }
      } else {
#pragma unroll
        for (int mt = 0; mt < 4; ++mt)
          acc[mt][nt] = __builtin_amdgcn_mfma_f32_16x16x32_bf16(afh[mt], bfh, acc[mt][nt], 0, 0, 0);
      }
    }
  }

  // epilogue
#pragma unroll
  for (int mt = 0; mt < 4; ++mt) {
    float scalev[4] = {1.f, 1.f, 1.f, 1.f};
    if constexpr (L2N) {
      // rows mt*16 + quad*4 + r; wave's 64 cols = one head group
#pragma unroll
      for (int rr = 0; rr < 4; ++rr) {
        float ss = 0.f;
#pragma unroll
        for (int nt = 0; nt < 4; ++nt) ss += acc[mt][nt][rr] * acc[mt][nt][rr];
        ss += __shfl_xor(ss, 1, 64);
        ss += __shfl_xor(ss, 2, 64);
        ss += __shfl_xor(ss, 4, 64);
        ss += __shfl_xor(ss, 8, 64);
        scalev[rr] = 1.0f / fmaxf(sqrtf(ss), 1e-12f);
      }
    }
#pragma unroll
    for (int nt = 0; nt < 4; ++nt) {
#pragma unroll
      for (int rr = 0; rr < 4; ++rr) {
        const int row = m0 + wm * 64 + mt * 16 + quad * 4 + rr;
        const int col = n0 + wn * 64 + nt * 16 + n15;
        const float v = acc[mt][nt][rr] * scalev[rr];
        if constexpr (F32OUT)
          ((float*)Cv)[(size_t)row * N + col] = v;
        else
          ((unsigned short*)Cv)[(size_t)row * N + col] = f2bf(v);
      }
    }
  }
}

// ---------------------------------------------------------------------------
// MFMA bf16 attention (unchanged from R2). Fixed softmax max = invt.
// ---------------------------------------------------------------------------
#define KC 128
#define KSPLIT 2
#define KSTR 72
#define VSTR 136
#define PSTR 72

__global__ __launch_bounds__(256, 3) void attn_mfma(
    const unsigned short* __restrict__ qb,   // [B1][768] bf16, normalized
    const unsigned short* __restrict__ kb,   // [B2][768] bf16, normalized
    const unsigned short* __restrict__ vt,   // [768][B2] bf16 (v transposed)
    float* __restrict__ aoacc,               // [B1][768] f32, zeroed
    float* __restrict__ lacc,                // [B1][NH] f32, zeroed
    const int* __restrict__ invt_p) {
  __shared__ unsigned short Kl[KC * KSTR];
  __shared__ unsigned short Vl[DH * VSTR];
  __shared__ unsigned short Psl[4 * 32 * PSTR];

  const float scale = (float)invt_p[0];
  const int h = blockIdx.y;
  const int q0 = blockIdx.x * 64;
  const int tid = threadIdx.x;
  const int wave = tid >> 6;
  const int lane = tid & 63;
  const int qsub = wave >> 1;
  const int ksub = wave & 1;
  const int n15 = lane & 15;
  const int quad = lane >> 4;
  const int kz0 = blockIdx.z * (B2 / KSPLIT);

  unsigned short* Ps = &Psl[wave * 32 * PSTR];

  short8 qf[2][2];
#pragma unroll
  for (int qt = 0; qt < 2; ++qt)
#pragma unroll
    for (int s = 0; s < 2; ++s) {
      const int qrow = q0 + qsub * 32 + qt * 16 + n15;
      qf[qt][s] = *(const short8*)&qb[(size_t)qrow * DMODEL + h * DH + s * 32 + quad * 8];
    }

  floatx4 oacc[2][4];
#pragma unroll
  for (int qt = 0; qt < 2; ++qt)
#pragma unroll
    for (int nt = 0; nt < 4; ++nt) oacc[qt][nt] = (floatx4){0.f, 0.f, 0.f, 0.f};
  float lsum[2][4];
#pragma unroll
  for (int qt = 0; qt < 2; ++qt)
#pragma unroll
    for (int r = 0; r < 4; ++r) lsum[qt][r] = 0.0f;

  for (int c = 0; c < B2 / KSPLIT; c += KC) {
    const int kc0 = kz0 + c;
    __syncthreads();
#pragma unroll
    for (int i = 0; i < 4; ++i) {
      const int slot = i * 256 + tid;
      const int key = slot >> 3, g = slot & 7;
      *(short8*)&Kl[key * KSTR + g * 8] =
          *(const short8*)&kb[(size_t)(kc0 + key) * DMODEL + h * DH + g * 8];
    }
#pragma unroll
    for (int i = 0; i < 4; ++i) {
      const int slot = i * 256 + tid;
      const int d = slot >> 4, g = slot & 15;
      *(short8*)&Vl[d * VSTR + g * 8] =
          *(const short8*)&vt[(size_t)(h * DH + d) * B2 + kc0 + g * 8];
    }
    __syncthreads();

#pragma unroll
    for (int nt = 0; nt < 4; ++nt) {
      floatx4 s0 = {0.f, 0.f, 0.f, 0.f}, s1 = {0.f, 0.f, 0.f, 0.f};
#pragma unroll
      for (int ks = 0; ks < 2; ++ks) {
        const short8 bfr = *(const short8*)&Kl[(ksub * 64 + nt * 16 + n15) * KSTR +
                                               ks * 32 + quad * 8];
        s0 = __builtin_amdgcn_mfma_f32_16x16x32_bf16(qf[0][ks], bfr, s0, 0, 0, 0);
        s1 = __builtin_amdgcn_mfma_f32_16x16x32_bf16(qf[1][ks], bfr, s1, 0, 0, 0);
      }
#pragma unroll
      for (int r = 0; r < 4; ++r) {
        const float p0 = __expf(scale * (s0[r] - 1.0f));
        const float p1 = __expf(scale * (s1[r] - 1.0f));
        lsum[0][r] += p0;
        lsum[1][r] += p1;
        Ps[(0 * 16 + quad * 4 + r) * PSTR + nt * 16 + n15] = f2bf(p0);
        Ps[(1 * 16 + quad * 4 + r) * PSTR + nt * 16 + n15] = f2bf(p1);
      }
    }

#pragma unroll
    for (int ks = 0; ks < 2; ++ks) {
      short8 af[2];
#pragma unroll
      for (int qt = 0; qt < 2; ++qt)
        af[qt] = *(const short8*)&Ps[(qt * 16 + n15) * PSTR + ks * 32 + quad * 8];
#pragma unroll
      for (int nt = 0; nt < 4; ++nt) {
        const short8 bfr = *(const short8*)&Vl[(nt * 16 + n15) * VSTR + ksub * 64 +
                                               ks * 32 + quad * 8];
        oacc[0][nt] = __builtin_amdgcn_mfma_f32_16x16x32_bf16(af[0], bfr, oacc[0][nt], 0, 0, 0);
        oacc[1][nt] = __builtin_amdgcn_mfma_f32_16x16x32_bf16(af[1], bfr, oacc[1][nt], 0, 0, 0);
      }
    }
  }

#pragma unroll
  for (int qt = 0; qt < 2; ++qt)
#pragma unroll
    for (int r = 0; r < 4; ++r) {
      float v = lsum[qt][r];
      v += __shfl_xor(v, 1, 64);
      v += __shfl_xor(v, 2, 64);
      v += __shfl_xor(v, 4, 64);
      v += __shfl_xor(v, 8, 64);
      lsum[qt][r] = v;
    }

  __syncthreads();
  float* Osc = (float*)Kl;
  float* Lsc = (float*)Vl;
  if (ksub == 1) {
#pragma unroll
    for (int qt = 0; qt < 2; ++qt) {
#pragma unroll
      for (int nt = 0; nt < 4; ++nt)
#pragma unroll
        for (int r = 0; r < 4; ++r) {
          const int row = qsub * 32 + qt * 16 + quad * 4 + r;
          Osc[row * 65 + nt * 16 + n15] = oacc[qt][nt][r];
        }
      if (n15 == 0)
#pragma unroll
        for (int r = 0; r < 4; ++r)
          Lsc[qsub * 32 + qt * 16 + quad * 4 + r] = lsum[qt][r];
    }
  }
  __syncthreads();
  if (ksub == 0) {
#pragma unroll
    for (int qt = 0; qt < 2; ++qt) {
#pragma unroll
      for (int nt = 0; nt < 4; ++nt)
#pragma unroll
        for (int r = 0; r < 4; ++r) {
          const int row = qsub * 32 + qt * 16 + quad * 4 + r;
          const float v = oacc[qt][nt][r] + Osc[row * 65 + nt * 16 + n15];
          atomicAdd(&aoacc[(size_t)(q0 + row) * DMODEL + h * DH + nt * 16 + n15], v);
        }
      if (n15 == 0)
#pragma unroll
        for (int r = 0; r < 4; ++r) {
          const int row = qsub * 32 + qt * 16 + quad * 4 + r;
          atomicAdd(&lacc[(q0 + row) * NH + h], lsum[qt][r] + Lsc[row]);
        }
    }
  }
}

// ---------------------------------------------------------------------------
__global__ __launch_bounds__(256) void ao_normalize(const float* __restrict__ ao,
                                                    const float* __restrict__ l,
                                                    float* __restrict__ out) {
  const int row = blockIdx.x;
  const int t = threadIdx.x;
#pragma unroll
  for (int i = 0; i < 3; ++i) {
    const int d = t + i * 256;
    out[(size_t)row * DMODEL + d] =
        ao[(size_t)row * DMODEL + d] / l[row * NH + (d >> 6)];
  }
}

// ---------------------------------------------------------------------------
__global__ __launch_bounds__(256) void l2norm_rows768_out(
    const float* __restrict__ x, float* __restrict__ out) {
  const int row = blockIdx.x;
  const float* xr = &x[(size_t)row * DMODEL];
  float ss = 0.0f;
  float vals[3];
#pragma unroll
  for (int i = 0; i < 3; ++i) {
    vals[i] = xr[threadIdx.x + i * 256];
    ss += vals[i] * vals[i];
  }
#pragma unroll
  for (int off = 32; off > 0; off >>= 1) ss += __shfl_xor(ss, off, 64);
  __shared__ float ws[4];
  if ((threadIdx.x & 63) == 0) ws[threadIdx.x >> 6] = ss;
  __syncthreads();
  const float tot = ws[0] + ws[1] + ws[2] + ws[3];
  const float sc = 1.0f / fmaxf(sqrtf(tot), 1e-12f);
  float* orow = &out[(size_t)row * DMODEL];
#pragma unroll
  for (int i = 0; i < 3; ++i) orow[threadIdx.x + i * 256] = vals[i] * sc;
}

// ---------------------------------------------------------------------------
extern "C" void kernel_launch(void* const* d_in, const int* in_sizes, int n_in,
                              void* d_out, int out_size, void* d_ws,
                              size_t ws_size, hipStream_t stream) {
  const float* x1 = (const float*)d_in[0];
  const float* x2 = (const float*)d_in[1];
  const float* Wq = (const float*)d_in[2];
  const float* Wk = (const float*)d_in[3];
  const float* Wv = (const float*)d_in[4];
  const float* Wo = (const float*)d_in[5];
  const int* invt = (const int*)d_in[6];
  float* outp = (float*)d_out;

  char* ws = (char*)d_ws;
  unsigned short* q_bf = (unsigned short*)(ws);                      // 3145728 B
  unsigned short* k_bf = (unsigned short*)(ws + 3145728);            // 12582912 B
  unsigned short* vt_bf = (unsigned short*)(ws + 15728640);          // 12582912 B
  float* aoacc = (float*)(ws + 28311552);                            // 6291456 B
  float* lacc = (float*)(ws + 34603008);                             // 98304 B
  float* aonorm = (float*)(ws + 34701312);                           // 6291456 B
  float* woout = (float*)(ws + 40992768);                            // 6291456 B

  // q/k projections: split-precision MFMA + fused per-head l2norm, bf16 out
  gemm_mfma<true, true, false><<<dim3(DMODEL / 128, B1 / 128), 256, 0, stream>>>(
      x1, Wq, q_bf, B1, DMODEL, DMODEL);
  gemm_mfma<true, true, false><<<dim3(DMODEL / 128, B2 / 128), 256, 0, stream>>>(
      x2, Wk, k_bf, B2, DMODEL, DMODEL);
  // v projection, produced transposed: vt = Wv @ x2^T, plain bf16 MFMA
  gemm_mfma<false, false, false><<<dim3(B2 / 128, DMODEL / 128), 256, 0, stream>>>(
      Wv, x2, vt_bf, DMODEL, B2, DMODEL);
  // zero accumulators (ws is poisoned each call)
  hipMemsetAsync(aoacc, 0, (size_t)B1 * DMODEL * sizeof(float), stream);
  hipMemsetAsync(lacc, 0, (size_t)B1 * NH * sizeof(float), stream);
  // attention (MFMA bf16)
  attn_mfma<<<dim3(B1 / 64, NH, KSPLIT), 256, 0, stream>>>(q_bf, k_bf, vt_bf,
                                                           aoacc, lacc, invt);
  ao_normalize<<<B1, 256, 0, stream>>>(aoacc, lacc, aonorm);
  // output projection: plain bf16 MFMA, f32 out
  gemm_mfma<false, false, true><<<dim3(DMODEL / 128, B1 / 128), 256, 0, stream>>>(
      aonorm, Wo, woout, B1, DMODEL, DMODEL);
  l2norm_rows768_out<<<B1, 256, 0, stream>>>(woout, outp);
}